// Round 1
// baseline (51.523 us; speedup 1.0000x reference)
//
#include <hip/hip_runtime.h>
#include <hip/hip_bf16.h>
#include <climits>

// Problem constants: B=8, C=8, H=512, W=512
#define HWSZ 262144      // H*W
#define CHWSZ 2097152    // C*H*W

typedef short short8 __attribute__((ext_vector_type(8)));   // 8 bf16 (4 VGPRs)
typedef float f32x4 __attribute__((ext_vector_type(4)));    // MFMA accumulator

// ---------------- init: zero norms, INT_MAX mins ----------------
__global__ __launch_bounds__(256) void hd_init(float* x2, float* y2, int* rowmin, int* colmin) {
    int i = blockIdx.x * 256 + threadIdx.x;   // grid 16*256 = 4096 exactly
    x2[i] = 0.0f;
    y2[i] = 0.0f;
    rowmin[i] = INT_MAX;
    colmin[i] = INT_MAX;
}

// ---------------- fused argmax + bf16 label write + row-norm accumulate ----------------
// One thread = 4 consecutive pixels (float4 per channel). A 64-lane wave covers 256
// consecutive pixels -> always within ONE (b, h) row, so one atomicAdd per wave.
__global__ __launch_bounds__(256) void hd_argmax(const float* __restrict__ logits,
                                                 const float* __restrict__ target,
                                                 ushort* __restrict__ lxb,
                                                 ushort* __restrict__ tyb,
                                                 float* __restrict__ x2,
                                                 float* __restrict__ y2) {
    int t = blockIdx.x * 256 + threadIdx.x;   // 0 .. 512K-1
    int p = t << 2;                           // pixel index
    int b = p >> 18;                          // / (H*W)
    int off = p & (HWSZ - 1);                 // offset within one batch image
    int h = off >> 9;                         // row
    int lane = threadIdx.x & 63;

    // ---- logits ----
    {
        const float4* L = (const float4*)(logits + (size_t)b * CHWSZ + off);
        float4 bv = L[0];
        int ix = 0, iy = 0, iz = 0, iw = 0;
#pragma unroll
        for (int c = 1; c < 8; ++c) {
            float4 v = L[c * (HWSZ / 4)];
            if (v.x > bv.x) { bv.x = v.x; ix = c; }
            if (v.y > bv.y) { bv.y = v.y; iy = c; }
            if (v.z > bv.z) { bv.z = v.z; iz = c; }
            if (v.w > bv.w) { bv.w = v.w; iw = c; }
        }
        ushort4 ub;
        ub.x = (ushort)(__float_as_uint((float)ix) >> 16);  // exact bf16 for 0..7
        ub.y = (ushort)(__float_as_uint((float)iy) >> 16);
        ub.z = (ushort)(__float_as_uint((float)iz) >> 16);
        ub.w = (ushort)(__float_as_uint((float)iw) >> 16);
        *(ushort4*)(lxb + p) = ub;
        int s = ix*ix + iy*iy + iz*iz + iw*iw;
#pragma unroll
        for (int o = 32; o > 0; o >>= 1) s += __shfl_down(s, o, 64);
        if (lane == 0) atomicAdd(&x2[(b << 9) + h], (float)s);  // integer-valued: order-independent
    }
    // ---- target ----
    {
        const float4* T = (const float4*)(target + (size_t)b * CHWSZ + off);
        float4 bv = T[0];
        int ix = 0, iy = 0, iz = 0, iw = 0;
#pragma unroll
        for (int c = 1; c < 8; ++c) {
            float4 v = T[c * (HWSZ / 4)];
            if (v.x > bv.x) { bv.x = v.x; ix = c; }
            if (v.y > bv.y) { bv.y = v.y; iy = c; }
            if (v.z > bv.z) { bv.z = v.z; iz = c; }
            if (v.w > bv.w) { bv.w = v.w; iw = c; }
        }
        ushort4 ub;
        ub.x = (ushort)(__float_as_uint((float)ix) >> 16);
        ub.y = (ushort)(__float_as_uint((float)iy) >> 16);
        ub.z = (ushort)(__float_as_uint((float)iz) >> 16);
        ub.w = (ushort)(__float_as_uint((float)iw) >> 16);
        *(ushort4*)(tyb + p) = ub;
        int s = ix*ix + iy*iy + iz*iz + iw*iw;
#pragma unroll
        for (int o = 32; o > 0; o >>= 1) s += __shfl_down(s, o, 64);
        if (lane == 0) atomicAdd(&y2[(b << 9) + h], (float)s);
    }
}

// ---------------- 64x64-tile MFMA distance kernel ----------------
// Grid (64, 8): blockIdx.x = ti*8+tj tile of the 512x512 distance matrix, blockIdx.y = batch.
// 4 waves per block, wave (wr,wc) owns a 32x32 quadrant as 2x2 MFMA 16x16x32 frags.
// Fragments load straight from global (label maps are 512KB/batch -> L2-hot).
// d2 = x2[i] + y2[j] - 2*<x_i,y_j>  (exact integer), reduced via shfl + atomicMin.
__global__ __launch_bounds__(256) void hd_dist(const ushort* __restrict__ lxb,
                                               const ushort* __restrict__ tyb,
                                               const float* __restrict__ x2,
                                               const float* __restrict__ y2,
                                               int* __restrict__ rowmin,
                                               int* __restrict__ colmin) {
    int b = blockIdx.y;
    int ti = blockIdx.x >> 3, tj = blockIdx.x & 7;
    int tid = threadIdx.x;
    int l = tid & 63;
    int wv = tid >> 6;
    int wr = wv >> 1, wc = wv & 1;
    int lr = l & 15, lg = l >> 4;

    const ushort* X = lxb + b * HWSZ + (ti * 64 + wr * 32 + lr) * 512 + lg * 8;
    const ushort* Y = tyb + b * HWSZ + (tj * 64 + wc * 32 + lr) * 512 + lg * 8;

    f32x4 acc00 = {0.f, 0.f, 0.f, 0.f};
    f32x4 acc01 = {0.f, 0.f, 0.f, 0.f};
    f32x4 acc10 = {0.f, 0.f, 0.f, 0.f};
    f32x4 acc11 = {0.f, 0.f, 0.f, 0.f};

#pragma unroll 4
    for (int kk = 0; kk < 512; kk += 32) {
        short8 a0 = *(const short8*)(X + kk);
        short8 a1 = *(const short8*)(X + 8192 + kk);   // +16 rows
        short8 b0 = *(const short8*)(Y + kk);
        short8 b1 = *(const short8*)(Y + 8192 + kk);
        acc00 = __builtin_amdgcn_mfma_f32_16x16x32_bf16(a0, b0, acc00, 0, 0, 0);
        acc01 = __builtin_amdgcn_mfma_f32_16x16x32_bf16(a0, b1, acc01, 0, 0, 0);
        acc10 = __builtin_amdgcn_mfma_f32_16x16x32_bf16(a1, b0, acc10, 0, 0, 0);
        acc11 = __builtin_amdgcn_mfma_f32_16x16x32_bf16(a1, b1, acc11, 0, 0, 0);
    }

    // epilogue: norms + exact integer d2
    int rb = (b << 9) + ti * 64 + wr * 32;   // global row base (into per-batch 512)
    int cb = (b << 9) + tj * 64 + wc * 32;   // global col base
    float x2v0[4], x2v1[4];
#pragma unroll
    for (int r = 0; r < 4; ++r) {
        x2v0[r] = x2[rb + lg * 4 + r];
        x2v1[r] = x2[rb + 16 + lg * 4 + r];
    }
    float y2v0 = y2[cb + lr];
    float y2v1 = y2[cb + 16 + lr];

    int d2[2][2][4];
#pragma unroll
    for (int r = 0; r < 4; ++r) {
        d2[0][0][r] = (int)(fmaxf(fmaf(-2.0f, acc00[r], x2v0[r] + y2v0), 0.0f) + 0.5f);
        d2[0][1][r] = (int)(fmaxf(fmaf(-2.0f, acc01[r], x2v0[r] + y2v1), 0.0f) + 0.5f);
        d2[1][0][r] = (int)(fmaxf(fmaf(-2.0f, acc10[r], x2v1[r] + y2v0), 0.0f) + 0.5f);
        d2[1][1][r] = (int)(fmaxf(fmaf(-2.0f, acc11[r], x2v1[r] + y2v1), 0.0f) + 0.5f);
    }

    // row mins: row r is held by the 16 lanes sharing lg, one col each (C layout: col=l&15)
#pragma unroll
    for (int fi = 0; fi < 2; ++fi) {
#pragma unroll
        for (int r = 0; r < 4; ++r) {
            int m = min(d2[fi][0][r], d2[fi][1][r]);
            m = min(m, __shfl_xor(m, 1, 64));
            m = min(m, __shfl_xor(m, 2, 64));
            m = min(m, __shfl_xor(m, 4, 64));
            m = min(m, __shfl_xor(m, 8, 64));
            if (lr == 0) atomicMin(&rowmin[rb + fi * 16 + lg * 4 + r], m);
        }
    }
    // col mins: col is fixed per lane within a frag; reduce across the 4 lane-groups
#pragma unroll
    for (int fj = 0; fj < 2; ++fj) {
        int m;
        if (fj == 0) {
            m = min(min(min(d2[0][0][0], d2[0][0][1]), min(d2[0][0][2], d2[0][0][3])),
                    min(min(d2[1][0][0], d2[1][0][1]), min(d2[1][0][2], d2[1][0][3])));
        } else {
            m = min(min(min(d2[0][1][0], d2[0][1][1]), min(d2[0][1][2], d2[0][1][3])),
                    min(min(d2[1][1][0], d2[1][1][1]), min(d2[1][1][2], d2[1][1][3])));
        }
        m = min(m, __shfl_xor(m, 16, 64));
        m = min(m, __shfl_xor(m, 32, 64));
        if (lg == 0) atomicMin(&colmin[cb + fj * 16 + lr], m);
    }
}

// ---------------- final: per-batch max over (rowmin ∪ colmin), sqrt, mean ----------------
// hd_b = max(sqrt(max rowmin), sqrt(max colmin)) = sqrt(max over both arrays).
__global__ __launch_bounds__(512) void hd_final(const int* __restrict__ rowmin,
                                                const int* __restrict__ colmin,
                                                float* __restrict__ out) {
    int w = threadIdx.x >> 6, l = threadIdx.x & 63;   // wave w = batch w
    int m = 0;
#pragma unroll
    for (int j = 0; j < 512; j += 64) {
        m = max(m, rowmin[(w << 9) + j + l]);
        m = max(m, colmin[(w << 9) + j + l]);
    }
#pragma unroll
    for (int s = 32; s > 0; s >>= 1) m = max(m, __shfl_xor(m, s, 64));
    __shared__ float hd[8];
    if (l == 0) hd[w] = sqrtf((float)m);
    __syncthreads();
    if (threadIdx.x == 0) {
        float s = 0.0f;
#pragma unroll
        for (int i = 0; i < 8; ++i) s += hd[i];
        out[0] = s * 0.125f;
    }
}

extern "C" void kernel_launch(void* const* d_in, const int* in_sizes, int n_in,
                              void* d_out, int out_size, void* d_ws, size_t ws_size,
                              hipStream_t stream) {
    (void)in_sizes; (void)n_in; (void)out_size; (void)ws_size;
    const float* logits = (const float*)d_in[0];
    const float* target = (const float*)d_in[1];

    char* ws = (char*)d_ws;
    ushort* lxb = (ushort*)ws;                          // 2M bf16 = 4 MB
    ushort* tyb = (ushort*)(ws + (4u << 20));           // 4 MB
    float* x2   = (float*)(ws + (8u << 20));            // 4096 f32
    float* y2   = x2 + 4096;                            // 4096 f32
    int* rowmin = (int*)(y2 + 4096);                    // 4096 i32
    int* colmin = rowmin + 4096;                        // 4096 i32
    float* out  = (float*)d_out;

    hipLaunchKernelGGL(hd_init,   dim3(16),    dim3(256), 0, stream, x2, y2, rowmin, colmin);
    hipLaunchKernelGGL(hd_argmax, dim3(2048),  dim3(256), 0, stream, logits, target, lxb, tyb, x2, y2);
    hipLaunchKernelGGL(hd_dist,   dim3(64, 8), dim3(256), 0, stream, lxb, tyb, x2, y2, rowmin, colmin);
    hipLaunchKernelGGL(hd_final,  dim3(1),     dim3(512), 0, stream, rowmin, colmin, out);
}